// Round 1
// baseline (893.274 us; speedup 1.0000x reference)
//
#include <hip/hip_runtime.h>
#include <stdint.h>

#define B_ 2
#define C_ 96
#define D_ 24
#define H_ 56
#define W_ 56
#define E_ 384
#define HW_ (H_*W_)        // 3136
#define S_ (D_*HW_)        // 75264
#define N_ (B_*S_)         // 150528

static __device__ __forceinline__ float bf2f(unsigned short h){
    union { unsigned int u; float f; } v; v.u = ((unsigned int)h) << 16; return v.f;
}
static __device__ __forceinline__ unsigned short f2bf(float x){
    union { float f; unsigned int u; } v; v.f = x;
    unsigned int r = v.u + 0x7FFFu + ((v.u >> 16) & 1u);
    return (unsigned short)(r >> 16);
}

// ---------------- K1: depthwise 7x7x7 conv + bias -> ws1 (bf16, NCDHW) ----------
// tile: 4(d) x 8(h) x 56(w) outputs per block; halo tile 10x14x62 (pitch 64) in LDS.
// each thread computes 8 consecutive w outputs via a 14-float register window.
__global__ __launch_bounds__(256) void k1_dwconv(
    const float* __restrict__ x, const float* __restrict__ wk,
    const float* __restrict__ bias, unsigned short* __restrict__ ws1)
{
    __shared__ __align__(16) float tile[10*14*64];
    const int tt = blockIdx.x;              // 0..41 = dt*7 + ht
    const int dt = tt / 7, ht = tt % 7;
    const int c  = blockIdx.y;
    const int b  = blockIdx.z;
    const int d0 = dt*4, h0 = ht*8;
    const int tid = threadIdx.x;
    const float* xc = x + (size_t)(b*C_ + c) * S_;

    for (int idx = tid; idx < 10*14*62; idx += 256){
        int dd = idx / (14*62);
        int r  = idx - dd*(14*62);
        int hh = r / 62;
        int ww = r - hh*62;
        int d = d0 - 3 + dd, h = h0 - 3 + hh, w = ww - 3;
        float v = 0.f;
        if ((unsigned)d < D_ && (unsigned)h < H_ && (unsigned)w < W_)
            v = xc[d*HW_ + h*W_ + w];
        tile[(dd*14 + hh)*64 + ww] = v;
    }
    __syncthreads();

    const int wz = tid & 7, hz = (tid >> 3) & 7, dz = tid >> 6;
    if (wz < 7) {
        float acc[8];
        #pragma unroll
        for (int j=0;j<8;++j) acc[j]=0.f;
        const float* wkc = wk + c*343;          // block-uniform -> s_loads
        for (int kd=0; kd<7; ++kd){
          for (int kh=0; kh<7; ++kh){
            const float* wr = wkc + kd*49 + kh*7;
            float wv[7];
            #pragma unroll
            for (int k=0;k<7;++k) wv[k]=wr[k];
            const float* base = &tile[((dz+kd)*14 + (hz+kh))*64 + wz*8];
            float4 a0 = *(const float4*)(base);
            float4 a1 = *(const float4*)(base+4);
            float4 a2 = *(const float4*)(base+8);
            float2 a3 = *(const float2*)(base+12);
            float win[14] = {a0.x,a0.y,a0.z,a0.w, a1.x,a1.y,a1.z,a1.w,
                             a2.x,a2.y,a2.z,a2.w, a3.x,a3.y};
            #pragma unroll
            for (int kw=0;kw<7;++kw){
              #pragma unroll
              for (int j=0;j<8;++j)
                acc[j] = fmaf(win[kw+j], wv[kw], acc[j]);
            }
          }
        }
        const float bs = bias[c];
        unsigned int p0 = (unsigned)f2bf(acc[0]+bs) | ((unsigned)f2bf(acc[1]+bs)<<16);
        unsigned int p1 = (unsigned)f2bf(acc[2]+bs) | ((unsigned)f2bf(acc[3]+bs)<<16);
        unsigned int p2 = (unsigned)f2bf(acc[4]+bs) | ((unsigned)f2bf(acc[5]+bs)<<16);
        unsigned int p3 = (unsigned)f2bf(acc[6]+bs) | ((unsigned)f2bf(acc[7]+bs)<<16);
        size_t off = (size_t)(b*C_ + c)*S_ + (size_t)(d0+dz)*HW_ + (h0+hz)*W_ + wz*8;
        *(uint4*)(&ws1[off]) = make_uint4(p0,p1,p2,p3);
    }
}

// ------------- K2: LayerNorm + pwconv1 + exact GELU -> ws2 (bf16, [E][N]) -------
// 64 positions per block; LDS tile y[96][64]; thread (p,q) owns position p and
// e-range [q*96, q*96+96) in groups of 8 (w1 rows fetched as wave-uniform s_loads).
__global__ __launch_bounds__(256) void k2_ln_pw1(
    const unsigned short* __restrict__ ws1, const float* __restrict__ ln_w,
    const float* __restrict__ ln_b, const float* __restrict__ w1,
    const float* __restrict__ b1, unsigned short* __restrict__ ws2)
{
    __shared__ float ly[96*64];
    __shared__ float red1[256], red2[256];
    __shared__ float smu[64], srs[64];
    const int tid = threadIdx.x;
    const int p = tid & 63, q = tid >> 6;
    const int n0 = blockIdx.x * 64;
    const int b = n0 / S_;
    const int s0 = n0 - b*S_;
    const size_t basein = (size_t)(b*C_)*S_ + s0 + p;

    float sum=0.f, ssq=0.f;
    for (int i=0;i<24;++i){
        int c = q*24 + i;
        float v = bf2f(ws1[basein + (size_t)c*S_]);
        ly[c*64+p] = v;
        sum += v; ssq = fmaf(v,v,ssq);
    }
    red1[tid]=sum; red2[tid]=ssq;
    __syncthreads();
    if (q==0){
        float s1 = red1[p]+red1[64+p]+red1[128+p]+red1[192+p];
        float s2 = red2[p]+red2[64+p]+red2[128+p]+red2[192+p];
        float mu = s1 * (1.f/96.f);
        float var = s2*(1.f/96.f) - mu*mu;
        smu[p]=mu; srs[p]=rsqrtf(var + 1e-6f);
    }
    __syncthreads();
    {
        float mu = smu[p], rs = srs[p];
        for (int i=0;i<24;++i){
            int c = q*24+i;
            float v = ly[c*64+p];
            ly[c*64+p] = (v-mu)*rs*ln_w[c] + ln_b[c];
        }
    }
    __syncthreads();

    const int e_base = __builtin_amdgcn_readfirstlane(q * 96);
    for (int g=0; g<12; ++g){
        const int e0 = e_base + g*8;
        float acc[8];
        #pragma unroll
        for (int j=0;j<8;++j) acc[j]=b1[e0+j];
        for (int c=0;c<96;++c){
            float yv = ly[c*64+p];
            const float* wr = w1 + c*E_ + e0;   // wave-uniform -> s_load
            #pragma unroll
            for (int j=0;j<8;++j)
                acc[j] = fmaf(yv, wr[j], acc[j]);
        }
        #pragma unroll
        for (int j=0;j<8;++j){
            float v = acc[j];
            float h = 0.5f*v*(1.f + erff(v*0.70710678118654752f));
            ws2[(size_t)(e0+j)*N_ + n0 + p] = f2bf(h);
        }
    }
}

// ---------- K3a: GRN sum of squares over spatial per (b,e) (no atomics) --------
__global__ __launch_bounds__(256) void k3a_grnsum(
    const unsigned short* __restrict__ ws2, float* __restrict__ gx2)
{
    const int bx = blockIdx.x;           // 0..767
    const int e = bx >> 1, b = bx & 1;
    const uint32_t* base = (const uint32_t*)(ws2 + (size_t)e*N_ + (size_t)b*S_);
    float ssq = 0.f;
    for (int i = threadIdx.x; i < S_/2; i += 256){
        uint32_t u = base[i];
        float f0 = __uint_as_float(u << 16);
        float f1 = __uint_as_float(u & 0xFFFF0000u);
        ssq = fmaf(f0,f0,ssq); ssq = fmaf(f1,f1,ssq);
    }
    #pragma unroll
    for (int off=32; off; off>>=1) ssq += __shfl_down(ssq, off);
    __shared__ float r[4];
    if ((threadIdx.x & 63)==0) r[threadIdx.x>>6] = ssq;
    __syncthreads();
    if (threadIdx.x==0) gx2[b*E_ + e] = r[0]+r[1]+r[2]+r[3];
}

// ---------- K3b: GRN scale s[b,e] = 1 + gamma[e] * nx[b,e] ----------------------
__global__ __launch_bounds__(384) void k3b_grnscale(
    const float* __restrict__ gx2, const float* __restrict__ gamma,
    float* __restrict__ sscale)
{
    const int b = blockIdx.x, e = threadIdx.x;
    float g = sqrtf(gx2[b*E_ + e]);
    float v = g;
    #pragma unroll
    for (int off=32; off; off>>=1) v += __shfl_down(v, off);
    __shared__ float r[6];
    __shared__ float mean_s;
    if ((e & 63)==0) r[e>>6] = v;
    __syncthreads();
    if (e==0) mean_s = (r[0]+r[1]+r[2]+r[3]+r[4]+r[5]) * (1.f/384.f);
    __syncthreads();
    float nx = g / (mean_s + 1e-6f);
    sscale[b*E_ + e] = 1.f + gamma[e]*nx;
}

// ---------- K3c: bc[j] = b2[j] + sum_e beta[e]*w2[e,j] --------------------------
__global__ __launch_bounds__(128) void k3c_bc(
    const float* __restrict__ b2, const float* __restrict__ beta,
    const float* __restrict__ w2, float* __restrict__ bc)
{
    int j = threadIdx.x;
    if (j < 96){
        float a = b2[j];
        for (int e=0;e<E_;++e) a = fmaf(beta[e], w2[e*C_ + j], a);
        bc[j] = a;
    }
}

// ---------- K4: GRN apply + pwconv2 + bias + residual -> out (fp32, NCDHW) ------
__global__ __launch_bounds__(256) void k4_pw2(
    const unsigned short* __restrict__ ws2, const float* __restrict__ sscale,
    const float* __restrict__ w2, const float* __restrict__ bc,
    const float* __restrict__ x, float* __restrict__ out)
{
    __shared__ float lh[192*64];
    const int tid = threadIdx.x;
    const int p = tid & 63, q = tid >> 6;
    const int n0 = blockIdx.x * 64;
    const int b = n0 / S_;
    const int s0 = n0 - b*S_;
    const int qu = __builtin_amdgcn_readfirstlane(q);

    float acc[24];
    #pragma unroll
    for (int j=0;j<24;++j) acc[j]=0.f;

    for (int half=0; half<2; ++half){
        __syncthreads();
        for (int i=0;i<48;++i){
            int el = qu*48 + i;
            int e = half*192 + el;
            float v = bf2f(ws2[(size_t)e*N_ + n0 + p]) * sscale[b*E_ + e];
            lh[el*64 + p] = v;
        }
        __syncthreads();
        const float* w2h = w2 + (size_t)(half*192)*C_ + qu*24;  // wave-uniform
        for (int el=0; el<192; ++el){
            float yv = lh[el*64+p];
            const float* wr = w2h + el*C_;
            #pragma unroll
            for (int j=0;j<24;++j)
                acc[j] = fmaf(yv, wr[j], acc[j]);
        }
    }

    const size_t obase = ((size_t)(b*C_ + qu*24))*S_ + s0 + p;
    #pragma unroll
    for (int j=0;j<24;++j){
        size_t a = obase + (size_t)j*S_;
        out[a] = acc[j] + bc[qu*24+j] + x[a];
    }
}

extern "C" void kernel_launch(void* const* d_in, const int* in_sizes, int n_in,
                              void* d_out, int out_size, void* d_ws, size_t ws_size,
                              hipStream_t stream)
{
    const float* x     = (const float*)d_in[0];
    const float* dwk   = (const float*)d_in[1];
    const float* dwb   = (const float*)d_in[2];
    const float* ln_w  = (const float*)d_in[3];
    const float* ln_b  = (const float*)d_in[4];
    const float* w1    = (const float*)d_in[5];
    const float* b1    = (const float*)d_in[6];
    const float* gamma = (const float*)d_in[7];
    const float* beta  = (const float*)d_in[8];
    const float* w2    = (const float*)d_in[9];
    const float* b2    = (const float*)d_in[10];
    float* out = (float*)d_out;

    char* ws = (char*)d_ws;
    unsigned short* ws1 = (unsigned short*)ws;                       // 57,802,752 B
    unsigned short* ws2 = (unsigned short*)(ws + 57802752);          // 115,605,504 B
    float* gx2    = (float*)(ws + 57802752 + 115605504);             // B*E floats
    float* sscale = gx2 + B_*E_;
    float* bc     = sscale + B_*E_;

    k1_dwconv   <<<dim3(42,96,2), 256, 0, stream>>>(x, dwk, dwb, ws1);
    k2_ln_pw1   <<<dim3(N_/64),   256, 0, stream>>>(ws1, ln_w, ln_b, w1, b1, ws2);
    k3a_grnsum  <<<dim3(B_*E_),   256, 0, stream>>>(ws2, gx2);
    k3b_grnscale<<<dim3(B_),      384, 0, stream>>>(gx2, gamma, sscale);
    k3c_bc      <<<dim3(1),       128, 0, stream>>>(b2, beta, w2, bc);
    k4_pw2      <<<dim3(N_/64),   256, 0, stream>>>(ws2, sscale, w2, bc, x, out);
}

// Round 2
// 524.998 us; speedup vs baseline: 1.7015x; 1.7015x over previous
//
#include <hip/hip_runtime.h>
#include <stdint.h>

#define B_ 2
#define C_ 96
#define D_ 24
#define H_ 56
#define W_ 56
#define E_ 384
#define HW_ (H_*W_)        // 3136
#define S_ (D_*HW_)        // 75264
#define N_ (B_*S_)         // 150528

typedef __attribute__((ext_vector_type(8))) short bf16x8;
typedef __attribute__((ext_vector_type(4))) float f32x4;

static __device__ __forceinline__ float bf2f(unsigned short h){
    union { unsigned int u; float f; } v; v.u = ((unsigned int)h) << 16; return v.f;
}
static __device__ __forceinline__ unsigned short f2bf(float x){
    union { float f; unsigned int u; } v; v.f = x;
    unsigned int r = v.u + 0x7FFFu + ((v.u >> 16) & 1u);
    return (unsigned short)(r >> 16);
}

// ---------------- K1: depthwise 7x7x7 conv + bias -> ws1 (bf16, NCDHW) ----------
// tile: 4(d) x 8(h) x 56(w); halo 10x14x62, LDS pitch 68 floats (bank-uniform).
__global__ __launch_bounds__(256) void k1_dwconv(
    const float* __restrict__ x, const float* __restrict__ wk,
    const float* __restrict__ bias, unsigned short* __restrict__ ws1)
{
    __shared__ __align__(16) float tile[10*14*68];
    const int tt = blockIdx.x;              // 0..41 = dt*7 + ht
    const int dt = tt / 7, ht = tt % 7;
    const int c  = blockIdx.y;
    const int b  = blockIdx.z;
    const int d0 = dt*4, h0 = ht*8;
    const int tid = threadIdx.x;
    const float* xc = x + (size_t)(b*C_ + c) * S_;

    for (int idx = tid; idx < 10*14*62; idx += 256){
        int dd = idx / (14*62);
        int r  = idx - dd*(14*62);
        int hh = r / 62;
        int ww = r - hh*62;
        int d = d0 - 3 + dd, h = h0 - 3 + hh, w = ww - 3;
        float v = 0.f;
        if ((unsigned)d < D_ && (unsigned)h < H_ && (unsigned)w < W_)
            v = xc[d*HW_ + h*W_ + w];
        tile[(dd*14 + hh)*68 + ww] = v;
    }
    __syncthreads();

    const int wz = tid & 7, hz = (tid >> 3) & 7, dz = tid >> 6;
    if (wz < 7) {
        float acc[8];
        #pragma unroll
        for (int j=0;j<8;++j) acc[j]=0.f;
        const float* wkc = wk + c*343;          // block-uniform -> s_loads
        for (int kd=0; kd<7; ++kd){
          for (int kh=0; kh<7; ++kh){
            const float* wr = wkc + kd*49 + kh*7;
            float wv[7];
            #pragma unroll
            for (int k=0;k<7;++k) wv[k]=wr[k];
            const float* base = &tile[((dz+kd)*14 + (hz+kh))*68 + wz*8];
            float4 a0 = *(const float4*)(base);
            float4 a1 = *(const float4*)(base+4);
            float4 a2 = *(const float4*)(base+8);
            float2 a3 = *(const float2*)(base+12);
            float win[14] = {a0.x,a0.y,a0.z,a0.w, a1.x,a1.y,a1.z,a1.w,
                             a2.x,a2.y,a2.z,a2.w, a3.x,a3.y};
            #pragma unroll
            for (int kw=0;kw<7;++kw){
              #pragma unroll
              for (int j=0;j<8;++j)
                acc[j] = fmaf(win[kw+j], wv[kw], acc[j]);
            }
          }
        }
        const float bs = bias[c];
        unsigned int p0 = (unsigned)f2bf(acc[0]+bs) | ((unsigned)f2bf(acc[1]+bs)<<16);
        unsigned int p1 = (unsigned)f2bf(acc[2]+bs) | ((unsigned)f2bf(acc[3]+bs)<<16);
        unsigned int p2 = (unsigned)f2bf(acc[4]+bs) | ((unsigned)f2bf(acc[5]+bs)<<16);
        unsigned int p3 = (unsigned)f2bf(acc[6]+bs) | ((unsigned)f2bf(acc[7]+bs)<<16);
        size_t off = (size_t)(b*C_ + c)*S_ + (size_t)(d0+dz)*HW_ + (h0+hz)*W_ + wz*8;
        *(uint4*)(&ws1[off]) = make_uint4(p0,p1,p2,p3);
    }
}

// ---------- kw1t: w1 [C][E] f32 -> w1t [E][C] bf16 ------------------------------
__global__ __launch_bounds__(256) void kw1t(
    const float* __restrict__ w1, unsigned short* __restrict__ w1t)
{
    int idx = blockIdx.x*256 + threadIdx.x;
    if (idx < E_*C_){
        int e = idx / C_, c = idx % C_;
        w1t[idx] = f2bf(w1[c*E_ + e]);
    }
}

// ------------- K2: LayerNorm + pwconv1(MFMA) + exact GELU -> ws2 bf16 [N][E] ----
// 64 positions/block, 4 waves. LN tile bf16 [64][104] in LDS (pad for banks).
// GEMM: M=pos(64), N=E(384), K=C(96). wave w owns m-tile w (16 pos), 24 n-tiles.
__global__ __launch_bounds__(256) void k2_ln_pw1(
    const unsigned short* __restrict__ ws1, const float* __restrict__ ln_w,
    const float* __restrict__ ln_b, const unsigned short* __restrict__ w1t,
    const float* __restrict__ b1, unsigned short* __restrict__ ws2)
{
    __shared__ unsigned short ly[64*104];
    __shared__ float red1[256], red2[256];
    __shared__ float smu[64], srs[64];
    const int tid = threadIdx.x;
    const int p = tid & 63, q = tid >> 6;
    const int n0 = blockIdx.x * 64;
    const int b = n0 / S_;
    const int s0 = n0 - b*S_;
    const size_t basein = (size_t)(b*C_)*S_ + s0 + p;

    float v[24];
    float sum=0.f, ssq=0.f;
    #pragma unroll
    for (int i=0;i<24;++i){
        int c = q*24 + i;
        float t = bf2f(ws1[basein + (size_t)c*S_]);
        v[i] = t; sum += t; ssq = fmaf(t,t,ssq);
    }
    red1[tid]=sum; red2[tid]=ssq;
    __syncthreads();
    if (q==0){
        float s1 = red1[p]+red1[64+p]+red1[128+p]+red1[192+p];
        float s2 = red2[p]+red2[64+p]+red2[128+p]+red2[192+p];
        float mu = s1 * (1.f/96.f);
        float var = s2*(1.f/96.f) - mu*mu;
        smu[p]=mu; srs[p]=rsqrtf(var + 1e-6f);
    }
    __syncthreads();
    {
        float mu = smu[p], rs = srs[p];
        #pragma unroll
        for (int i=0;i<24;++i){
            int c = q*24+i;
            ly[p*104 + c] = f2bf((v[i]-mu)*rs*ln_w[c] + ln_b[c]);
        }
    }
    __syncthreads();

    const int lane = tid & 63;
    const int lr = lane & 15;   // D col / A row within tile
    const int lk = lane >> 4;   // k-block
    bf16x8 af[3];
    #pragma unroll
    for (int kk=0;kk<3;++kk)
        af[kk] = *(const bf16x8*)&ly[(q*16 + lr)*104 + kk*32 + lk*8];

    for (int nt=0; nt<24; ++nt){
        f32x4 acc = {0.f,0.f,0.f,0.f};
        #pragma unroll
        for (int kk=0;kk<3;++kk){
            bf16x8 bfr = *(const bf16x8*)&w1t[(size_t)(nt*16 + lr)*C_ + kk*32 + lk*8];
            acc = __builtin_amdgcn_mfma_f32_16x16x32_bf16(af[kk], bfr, acc, 0, 0, 0);
        }
        float bias = b1[nt*16 + lr];
        #pragma unroll
        for (int r=0;r<4;++r){
            float val = acc[r] + bias;
            float g = 0.5f*val*(1.f + erff(val*0.70710678118654752f));
            int pos = q*16 + lk*4 + r;
            ws2[(size_t)(n0 + pos)*E_ + nt*16 + lr] = f2bf(g);
        }
    }
}

// ---------- K3a stage1: per-(b,chunk) partial sum of squares over 256 rows ------
__global__ __launch_bounds__(192) void k3a1(
    const unsigned short* __restrict__ ws2, float* __restrict__ partial)
{
    const int chunk = blockIdx.x, b = blockIdx.y;   // 294 chunks x 2 batches
    const uint32_t* base = (const uint32_t*)(ws2 + ((size_t)b*S_ + (size_t)chunk*256)*E_);
    const int t = threadIdx.x;   // owns e = 2t, 2t+1
    float a0=0.f, a1=0.f;
    for (int r=0;r<256;++r){
        uint32_t u = base[(size_t)r*192 + t];
        float f0 = __uint_as_float(u << 16);
        float f1 = __uint_as_float(u & 0xFFFF0000u);
        a0 = fmaf(f0,f0,a0); a1 = fmaf(f1,f1,a1);
    }
    float* dst = partial + ((size_t)(b*294 + chunk))*E_;
    dst[2*t] = a0; dst[2*t+1] = a1;
}

// ---------- K3a stage2: reduce partials -> gx2[b][e] ----------------------------
__global__ __launch_bounds__(384) void k3a2(
    const float* __restrict__ partial, float* __restrict__ gx2)
{
    const int b = blockIdx.x, e = threadIdx.x;
    float s = 0.f;
    for (int c=0;c<294;++c) s += partial[((size_t)(b*294 + c))*E_ + e];
    gx2[b*E_ + e] = s;
}

// ---------- K3b: GRN scale s[b,e] = 1 + gamma[e]*nx[b,e] ------------------------
__global__ __launch_bounds__(384) void k3b_grnscale(
    const float* __restrict__ gx2, const float* __restrict__ gamma,
    float* __restrict__ sscale)
{
    const int b = blockIdx.x, e = threadIdx.x;
    float g = sqrtf(gx2[b*E_ + e]);
    float v = g;
    #pragma unroll
    for (int off=32; off; off>>=1) v += __shfl_down(v, off);
    __shared__ float r[6];
    __shared__ float mean_s;
    if ((e & 63)==0) r[e>>6] = v;
    __syncthreads();
    if (e==0) mean_s = (r[0]+r[1]+r[2]+r[3]+r[4]+r[5]) * (1.f/384.f);
    __syncthreads();
    float nx = g / (mean_s + 1e-6f);
    sscale[b*E_ + e] = 1.f + gamma[e]*nx;
}

// ---------- kw2s: w2s[b][c][e] = w2[e][c]*sscale[b][e] in bf16 -------------------
__global__ __launch_bounds__(256) void kw2s(
    const float* __restrict__ w2, const float* __restrict__ sscale,
    unsigned short* __restrict__ w2s)
{
    int idx = blockIdx.x*256 + threadIdx.x;
    if (idx < 2*C_*E_){
        int b = idx / (C_*E_);
        int rem = idx - b*(C_*E_);
        int c = rem / E_, e = rem % E_;
        w2s[idx] = f2bf(w2[e*C_ + c] * sscale[b*E_ + e]);
    }
}

// ---------- K3c: bc[j] = b2[j] + sum_e beta[e]*w2[e,j] --------------------------
__global__ __launch_bounds__(128) void k3c_bc(
    const float* __restrict__ b2, const float* __restrict__ beta,
    const float* __restrict__ w2, float* __restrict__ bc)
{
    int j = threadIdx.x;
    if (j < 96){
        float a = b2[j];
        for (int e=0;e<E_;++e) a = fmaf(beta[e], w2[e*C_ + j], a);
        bc[j] = a;
    }
}

// ---------- K4: pwconv2(MFMA, GRN folded into w2s) + bias + residual ------------
// GEMM: M=C(96), N=pos(64), K=E(384). B-tile = ws2 rows, contiguous copy to LDS.
__global__ __launch_bounds__(256) void k4_pw2(
    const unsigned short* __restrict__ ws2, const unsigned short* __restrict__ w2s,
    const float* __restrict__ bc, const float* __restrict__ x,
    float* __restrict__ out)
{
    __shared__ unsigned short bh[64*392];
    const int tid = threadIdx.x;
    const int n0 = blockIdx.x * 64;
    const int b = n0 / S_;
    const int s0 = n0 - b*S_;

    const uint4* src = (const uint4*)(ws2 + (size_t)n0*E_);
    for (int i = tid; i < 3072; i += 256){
        int row = i / 48, cc = i - (i/48)*48;
        *(uint4*)&bh[row*392 + cc*8] = src[i];
    }
    __syncthreads();

    const int lane = tid & 63, q = tid >> 6;
    const int lr = lane & 15, lk = lane >> 4;
    f32x4 acc[6];
    #pragma unroll
    for (int m=0;m<6;++m) acc[m] = (f32x4){0.f,0.f,0.f,0.f};
    const unsigned short* w2sb = w2s + (size_t)b*C_*E_;

    for (int kk=0; kk<12; ++kk){
        bf16x8 bfr = *(const bf16x8*)&bh[(q*16 + lr)*392 + kk*32 + lk*8];
        #pragma unroll
        for (int m=0;m<6;++m){
            bf16x8 afr = *(const bf16x8*)&w2sb[(size_t)(m*16 + lr)*E_ + kk*32 + lk*8];
            acc[m] = __builtin_amdgcn_mfma_f32_16x16x32_bf16(afr, bfr, acc[m], 0, 0, 0);
        }
    }

    const int pos = q*16 + lr;
    const size_t sidx = (size_t)s0 + pos;
    #pragma unroll
    for (int m=0;m<6;++m){
        #pragma unroll
        for (int r=0;r<4;++r){
            int c = m*16 + lk*4 + r;
            size_t a = ((size_t)(b*C_ + c))*S_ + sidx;
            out[a] = acc[m][r] + bc[c] + x[a];
        }
    }
}

extern "C" void kernel_launch(void* const* d_in, const int* in_sizes, int n_in,
                              void* d_out, int out_size, void* d_ws, size_t ws_size,
                              hipStream_t stream)
{
    const float* x     = (const float*)d_in[0];
    const float* dwk   = (const float*)d_in[1];
    const float* dwb   = (const float*)d_in[2];
    const float* ln_w  = (const float*)d_in[3];
    const float* ln_b  = (const float*)d_in[4];
    const float* w1    = (const float*)d_in[5];
    const float* b1    = (const float*)d_in[6];
    const float* gamma = (const float*)d_in[7];
    const float* beta  = (const float*)d_in[8];
    const float* w2    = (const float*)d_in[9];
    const float* b2    = (const float*)d_in[10];
    float* out = (float*)d_out;

    char* ws = (char*)d_ws;
    unsigned short* ws1 = (unsigned short*)ws;                        // 57,802,752 B
    unsigned short* ws2 = (unsigned short*)(ws + 57802752);           // 115,605,504 B
    unsigned short* w1t = (unsigned short*)(ws + 173408256);          // 73,728 B
    float* gx2    = (float*)(ws + 173408256 + 73728);                 // 3,072 B
    float* sscale = gx2 + B_*E_;                                      // 3,072 B
    float* bc     = sscale + B_*E_;                                   // 384 B
    // Aliased into ws1 region (ws1 dead after k2):
    unsigned short* w2s  = (unsigned short*)ws;                       // 147,456 B
    float* partial = (float*)(ws + 1048576);                          // 903,168 B

    k1_dwconv   <<<dim3(42,96,2), 256, 0, stream>>>(x, dwk, dwb, ws1);
    kw1t        <<<dim3(144),     256, 0, stream>>>(w1, w1t);
    k2_ln_pw1   <<<dim3(N_/64),   256, 0, stream>>>(ws1, ln_w, ln_b, w1t, b1, ws2);
    k3a1        <<<dim3(294,2),   192, 0, stream>>>(ws2, partial);
    k3a2        <<<dim3(2),       384, 0, stream>>>(partial, gx2);
    k3b_grnscale<<<dim3(B_),      384, 0, stream>>>(gx2, gamma, sscale);
    kw2s        <<<dim3(288),     256, 0, stream>>>(w2, sscale, w2s);
    k3c_bc      <<<dim3(1),       128, 0, stream>>>(b2, beta, w2, bc);
    k4_pw2      <<<dim3(N_/64),   256, 0, stream>>>(ws2, w2s, bc, x, out);
}